// Round 1
// baseline (1169.564 us; speedup 1.0000x reference)
//
#include <hip/hip_runtime.h>
#include <hip/hip_bf16.h>
#include <math.h>

#define DEV __device__ __forceinline__

DEV float sigmoidf_(float x) { return 1.0f / (1.0f + __expf(-x)); }

// acc[i] += sum_k sbuf[i*STRIDE + k] * W[k*64 + c]   (single matrix)
template<int ROWS, int STRIDE, int K>
DEV void matvec1(const float* sbuf, const float* __restrict__ W, int c, float* acc) {
  for (int k4 = 0; k4 < K; k4 += 4) {
    const float w0 = W[(k4 + 0) * 64 + c];
    const float w1 = W[(k4 + 1) * 64 + c];
    const float w2 = W[(k4 + 2) * 64 + c];
    const float w3 = W[(k4 + 3) * 64 + c];
#pragma unroll
    for (int i = 0; i < ROWS; ++i) {
      const float4 v = *reinterpret_cast<const float4*>(&sbuf[i * STRIDE + k4]);
      acc[i] = fmaf(v.x, w0, acc[i]);
      acc[i] = fmaf(v.y, w1, acc[i]);
      acc[i] = fmaf(v.z, w2, acc[i]);
      acc[i] = fmaf(v.w, w3, acc[i]);
    }
  }
}

// two matrices sharing the same LDS operand (z and r gates in one pass)
template<int ROWS, int STRIDE, int K>
DEV void matvec2(const float* sbuf, const float* __restrict__ Wa, const float* __restrict__ Wb,
                 int c, float* accA, float* accB) {
  for (int k4 = 0; k4 < K; k4 += 4) {
    const float wa0 = Wa[(k4 + 0) * 64 + c];
    const float wa1 = Wa[(k4 + 1) * 64 + c];
    const float wa2 = Wa[(k4 + 2) * 64 + c];
    const float wa3 = Wa[(k4 + 3) * 64 + c];
    const float wb0 = Wb[(k4 + 0) * 64 + c];
    const float wb1 = Wb[(k4 + 1) * 64 + c];
    const float wb2 = Wb[(k4 + 2) * 64 + c];
    const float wb3 = Wb[(k4 + 3) * 64 + c];
#pragma unroll
    for (int i = 0; i < ROWS; ++i) {
      const float4 v = *reinterpret_cast<const float4*>(&sbuf[i * STRIDE + k4]);
      accA[i] = fmaf(v.x, wa0, accA[i]);
      accA[i] = fmaf(v.y, wa1, accA[i]);
      accA[i] = fmaf(v.z, wa2, accA[i]);
      accA[i] = fmaf(v.w, wa3, accA[i]);
      accB[i] = fmaf(v.x, wb0, accB[i]);
      accB[i] = fmaf(v.y, wb1, accB[i]);
      accB[i] = fmaf(v.z, wb2, accB[i]);
      accB[i] = fmaf(v.w, wb3, accB[i]);
    }
  }
}

DEV float gstep(float x, float h, const float* k, const float* rk, const float* bb) {
  const float z  = sigmoidf_(fmaf(x, k[0], bb[0]) + fmaf(h, rk[0], bb[3]));
  const float r  = sigmoidf_(fmaf(x, k[1], bb[1]) + fmaf(h, rk[1], bb[4]));
  const float hh = tanhf(fmaf(x, k[2], bb[2]) + r * fmaf(h, rk[2], bb[5]));
  return z * h + (1.f - z) * hh;
}

// 3 tiny sequential bidirectional GRU chains + softmax + gather -> tp[3][60]
__global__ void temporal_kernel(const float* __restrict__ T, const float* __restrict__ GK,
                                const float* __restrict__ GRK, const float* __restrict__ GB,
                                const float* __restrict__ WO, const int* __restrict__ IDX,
                                float* __restrict__ tp) {
  const int i = threadIdx.x;
  __shared__ float fb[3][75];
  __shared__ float gg[3][75];
  if (i < 3) {
    float k0[3], k1[3], rk0[3], rk1[3];
#pragma unroll
    for (int q = 0; q < 3; ++q) {
      k0[q]  = GK[i * 6 + q];      k1[q]  = GK[i * 6 + 3 + q];
      rk0[q] = GRK[i * 6 + q];     rk1[q] = GRK[i * 6 + 3 + q];
    }
    const float* B0 = GB + i * 12;      // [p][q] for scan 0
    const float* B1 = GB + i * 12 + 6;  // [p][q] for scan 1
    float h = 0.f;
    for (int s = 0; s < 75; ++s) { h = gstep(T[i * 75 + s], h, k0, rk0, B0); fb[i][s] = h; }
    h = 0.f;
    for (int s = 0; s < 75; ++s) { h = gstep(fb[i][74 - s], h, k1, rk1, B1); gg[i][s] = h; }
    const float wo = WO[i];
    float mx = -1e30f;
    for (int s = 0; s < 75; ++s) mx = fmaxf(mx, gg[i][s] * wo);
    float sum = 0.f;
    for (int s = 0; s < 75; ++s) { const float e = __expf(gg[i][s] * wo - mx); fb[i][s] = e; sum += e; }
    const float inv = 1.f / sum;
    for (int j = 0; j < 60; ++j) tp[i * 60 + j] = fb[i][IDX[j]] * inv;
  }
}

// One wave (64 threads) per batch element. lane = feature column c.
// h_R (1), h_O (10), h_D (11) live in registers, column-distributed.
__global__ void ggnn_main(
    const float* __restrict__ X, const float* __restrict__ A,
    const float* __restrict__ WgR, const float* __restrict__ bgR,
    const float* __restrict__ WgO, const float* __restrict__ bgO,
    const float* __restrict__ WgD, const float* __restrict__ bgD,
    const float* __restrict__ WzR, const float* __restrict__ WrR,
    const float* __restrict__ WmR, const float* __restrict__ bmR,
    const float* __restrict__ WzO, const float* __restrict__ WrO,
    const float* __restrict__ WmO, const float* __restrict__ bmO,
    const float* __restrict__ WzD, const float* __restrict__ WrD,
    const float* __restrict__ WmD, const float* __restrict__ bmD,
    const float* __restrict__ W1R, const float* __restrict__ b1R, const float* __restrict__ W2R,
    const float* __restrict__ W1O, const float* __restrict__ b1O, const float* __restrict__ W2O,
    const float* __restrict__ W1D, const float* __restrict__ b1D, const float* __restrict__ W2D,
    const float* __restrict__ tp, float* __restrict__ out) {
  const int b = blockIdx.x;
  const int c = threadIdx.x;  // 0..63

  __shared__ __align__(16) float smem[1920];  // X stage (880) / gate-hn stage (<=10x192)
  __shared__ float sA[484];                   // A[b] 22x22

  const float* Xb = X + (size_t)b * 880;
  const float* Ab = A + (size_t)b * 484;
  for (int t = c; t < 880; t += 64) smem[t] = Xb[t];
  for (int t = c; t < 484; t += 64) sA[t] = Ab[t];
  __syncthreads();

  // ---------------- phase 0: h = tanh(Xg @ Wg + bg) ----------------
  float hR;
  float hO[10], hD[11];
  {
    float aR = bgR[c], cO = bgO[c], cD = bgD[c];
#pragma unroll
    for (int k = 0; k < 40; ++k) {
      const float x = smem[k];  // X[b,0,k] broadcast
      aR = fmaf(x, WgR[k * 64 + c], aR);
      cO = fmaf(x, WgO[k * 64 + c], cO);
      cD = fmaf(x, WgD[k * 64 + c], cD);
    }
    hR = tanhf(aR);
    float aO[10], aD[11];
#pragma unroll
    for (int i = 0; i < 10; ++i) aO[i] = cO;
#pragma unroll
    for (int i = 0; i < 11; ++i) aD[i] = cD;
    for (int k = 0; k < 30; ++k) {
      const float wo_ = WgO[(40 + k) * 64 + c];
      const float wd_ = WgD[(40 + k) * 64 + c];
#pragma unroll
      for (int i = 0; i < 10; ++i) aO[i] = fmaf(smem[(1 + i) * 40 + 10 + k], wo_, aO[i]);
#pragma unroll
      for (int i = 0; i < 11; ++i) aD[i] = fmaf(smem[(11 + i) * 40 + 10 + k], wd_, aD[i]);
    }
#pragma unroll
    for (int i = 0; i < 10; ++i) hO[i] = tanhf(aO[i]);
#pragma unroll
    for (int i = 0; i < 11; ++i) hD[i] = tanhf(aD[i]);
  }

  // ---------------- 3 GRU iterations ----------------
  for (int it = 0; it < 3; ++it) {
    // n-messages (registers + broadcast A scalars)
    float nR = 0.f;
#pragma unroll
    for (int i = 0; i < 10; ++i) nR = fmaf(sA[1 + i], hO[i], nR);
    float nO1[10], nO2[10], nD[11];
#pragma unroll
    for (int i = 0; i < 10; ++i) nO1[i] = sA[(1 + i) * 22] * hR;
#pragma unroll
    for (int i = 0; i < 10; ++i) {
      float a = 0.f;
#pragma unroll
      for (int j = 0; j < 11; ++j) a = fmaf(sA[(1 + i) * 22 + 11 + j], hD[j], a);
      nO2[i] = a;
    }
#pragma unroll
    for (int i = 0; i < 11; ++i) {
      float a = 0.f;
#pragma unroll
      for (int j = 0; j < 10; ++j) a = fmaf(sA[(11 + i) * 22 + 1 + j], hO[j], a);
      nD[i] = a;
    }

    // ---- gate R (1 row, K=128) ----
    __syncthreads();
    smem[c] = hR;
    smem[64 + c] = nR;
    __syncthreads();
    {
      float az[1] = {0.f}, ar[1] = {0.f};
      matvec2<1, 128, 128>(smem, WzR, WrR, c, az, ar);
      const float z = sigmoidf_(az[0]);
      const float r = sigmoidf_(ar[0]);
      __syncthreads();
      smem[c] = hR * r;
      __syncthreads();
      float am[1] = {bmR[c]};
      matvec1<1, 128, 128>(smem, WmR, c, am);
      hR = (1.f - z) * hR + z * tanhf(am[0]);
    }

    // ---- gate O (10 rows, K=192) ----
    __syncthreads();
#pragma unroll
    for (int i = 0; i < 10; ++i) {
      smem[i * 192 + c] = hO[i];
      smem[i * 192 + 64 + c] = nO1[i];
      smem[i * 192 + 128 + c] = nO2[i];
    }
    __syncthreads();
    {
      float az[10], ar[10];
#pragma unroll
      for (int i = 0; i < 10; ++i) { az[i] = 0.f; ar[i] = 0.f; }
      matvec2<10, 192, 192>(smem, WzO, WrO, c, az, ar);
      float z[10], r[10];
#pragma unroll
      for (int i = 0; i < 10; ++i) { z[i] = sigmoidf_(az[i]); r[i] = sigmoidf_(ar[i]); }
      __syncthreads();
#pragma unroll
      for (int i = 0; i < 10; ++i) smem[i * 192 + c] = hO[i] * r[i];
      __syncthreads();
      float am[10];
#pragma unroll
      for (int i = 0; i < 10; ++i) am[i] = bmO[c];
      matvec1<10, 192, 192>(smem, WmO, c, am);
#pragma unroll
      for (int i = 0; i < 10; ++i) hO[i] = (1.f - z[i]) * hO[i] + z[i] * tanhf(am[i]);
    }

    // ---- gate D (11 rows, K=128) ----
    __syncthreads();
#pragma unroll
    for (int i = 0; i < 11; ++i) {
      smem[i * 128 + c] = hD[i];
      smem[i * 128 + 64 + c] = nD[i];
    }
    __syncthreads();
    {
      float az[11], ar[11];
#pragma unroll
      for (int i = 0; i < 11; ++i) { az[i] = 0.f; ar[i] = 0.f; }
      matvec2<11, 128, 128>(smem, WzD, WrD, c, az, ar);
      float z[11], r[11];
#pragma unroll
      for (int i = 0; i < 11; ++i) { z[i] = sigmoidf_(az[i]); r[i] = sigmoidf_(ar[i]); }
      __syncthreads();
#pragma unroll
      for (int i = 0; i < 11; ++i) smem[i * 128 + c] = hD[i] * r[i];
      __syncthreads();
      float am[11];
#pragma unroll
      for (int i = 0; i < 11; ++i) am[i] = bmD[c];
      matvec1<11, 128, 128>(smem, WmD, c, am);
#pragma unroll
      for (int i = 0; i < 11; ++i) hD[i] = (1.f - z[i]) * hD[i] + z[i] * tanhf(am[i]);
    }
  }

  // ---------------- scores ----------------
  __syncthreads();
  smem[c] = hR;
#pragma unroll
  for (int i = 0; i < 10; ++i) smem[(1 + i) * 64 + c] = hO[i];
#pragma unroll
  for (int i = 0; i < 11; ++i) smem[(11 + i) * 64 + c] = hD[i];
  __syncthreads();

  const int g = c >> 4;    // row-group 0..3
  const int c1 = c & 15;   // hidden-1 column
  float pR = 0.f, pO = 0.f, pD = 0.f;
  for (int rr = g; rr < 22; rr += 4) {
    const float* W1; const float* b1; const float* W2;
    if (rr == 0)      { W1 = W1R; b1 = b1R; W2 = W2R; }
    else if (rr < 11) { W1 = W1O; b1 = b1O; W2 = W2O; }
    else              { W1 = W1D; b1 = b1D; W2 = W2D; }
    float a = b1[c1];
#pragma unroll
    for (int kk = 0; kk < 64; ++kk) {
      const int k = (kk + (g << 4)) & 63;  // stagger to dodge LDS bank aliasing
      a = fmaf(smem[rr * 64 + k], W1[k * 16 + c1], a);
    }
    const float t = tanhf(a) * W2[c1];
    if (rr == 0) pR += t;
    else if (rr < 11) pO += t;
    else pD += t;
  }
#pragma unroll
  for (int off = 32; off >= 1; off >>= 1) {
    pR += __shfl_xor(pR, off, 64);
    pO += __shfl_xor(pO, off, 64);
    pD += __shfl_xor(pD, off, 64);
  }
  if (c < 60) {
    out[(size_t)b * 60 + c] = pR * tp[c] + pO * tp[60 + c] + pD * tp[120 + c];
  }
}

extern "C" void kernel_launch(void* const* d_in, const int* in_sizes, int n_in,
                              void* d_out, int out_size, void* d_ws, size_t ws_size,
                              hipStream_t stream) {
  const float* X   = (const float*)d_in[0];
  const float* A   = (const float*)d_in[1];
  const float* WgR = (const float*)d_in[2];
  const float* bgR = (const float*)d_in[3];
  const float* WgO = (const float*)d_in[4];
  const float* bgO = (const float*)d_in[5];
  const float* WgD = (const float*)d_in[6];
  const float* bgD = (const float*)d_in[7];
  const float* WzR = (const float*)d_in[8];
  const float* WrR = (const float*)d_in[9];
  const float* WmR = (const float*)d_in[10];
  const float* bmR = (const float*)d_in[11];
  const float* WzO = (const float*)d_in[12];
  const float* WrO = (const float*)d_in[13];
  const float* WmO = (const float*)d_in[14];
  const float* bmO = (const float*)d_in[15];
  const float* WzD = (const float*)d_in[16];
  const float* WrD = (const float*)d_in[17];
  const float* WmD = (const float*)d_in[18];
  const float* bmD = (const float*)d_in[19];
  const float* W1R = (const float*)d_in[20];
  const float* b1R = (const float*)d_in[21];
  const float* W2R = (const float*)d_in[22];
  const float* W1O = (const float*)d_in[23];
  const float* b1O = (const float*)d_in[24];
  const float* W2O = (const float*)d_in[25];
  const float* W1D = (const float*)d_in[26];
  const float* b1D = (const float*)d_in[27];
  const float* W2D = (const float*)d_in[28];
  const float* Tmp = (const float*)d_in[29];
  const float* GK  = (const float*)d_in[30];
  const float* GRK = (const float*)d_in[31];
  const float* GB  = (const float*)d_in[32];
  const float* WO  = (const float*)d_in[33];
  const int*   IDX = (const int*)d_in[34];

  float* tp = (float*)d_ws;  // 3*60 floats
  const int B = in_sizes[0] / 880;

  hipLaunchKernelGGL(temporal_kernel, dim3(1), dim3(64), 0, stream, Tmp, GK, GRK, GB, WO, IDX, tp);
  hipLaunchKernelGGL(ggnn_main, dim3(B), dim3(64), 0, stream,
                     X, A, WgR, bgR, WgO, bgO, WgD, bgD,
                     WzR, WrR, WmR, bmR, WzO, WrO, WmO, bmO, WzD, WrD, WmD, bmD,
                     W1R, b1R, W2R, W1O, b1O, W2O, W1D, b1D, W2D,
                     tp, (float*)d_out);
}